// Round 1
// baseline (774.591 us; speedup 1.0000x reference)
//
#include <hip/hip_runtime.h>
#include <cstddef>

#define B_    4096
#define N_    64
#define FEAT_ 172
#define DM_   516
#define DK_   258

// workspace layout (float offsets)
#define OFF_U      0
#define OFF_WVP    1032
#define OFF_WFCP   (1032 + 266256)
#define OFF_W1P    (1032 + 2*266256)
#define OFF_W2P    (1032 + 2*266256 + 118336)
#define OFF_CTXIN  (1032 + 2*266256 + 118336 + 29584)
// total floats = OFF_CTXIN + 4096*1032 = 4,908,536  (~18.7 MiB)

// ---------------------------------------------------------------------------
// prep: u[h][c] = sum_d Wk[h*258+d][c] * w_map[258+d]; repack weights as
// float4-along-input-dim, output-column-major: Wp4[c4*OUT + j] = W[j][4c4..4c4+3]
// ---------------------------------------------------------------------------
__global__ __launch_bounds__(256) void prep_kernel(
    const float* __restrict__ Wk, const float* __restrict__ wmap,
    const float* __restrict__ Wv, const float* __restrict__ Wfc,
    const float* __restrict__ W1, const float* __restrict__ W2,
    float* __restrict__ ws)
{
  int i = blockIdx.x * 256 + threadIdx.x;
  float*  u    = ws + OFF_U;
  float4* Wvp  = (float4*)(ws + OFF_WVP);
  float4* Wfcp = (float4*)(ws + OFF_WFCP);
  float4* W1p  = (float4*)(ws + OFF_W1P);
  float4* W2p  = (float4*)(ws + OFF_W2P);
  if (i < 66564) {                       // Wv: 129 c4 x 516 j
    int c4 = i / 516, j = i % 516;
    Wvp[i] = *(const float4*)&Wv[(size_t)j*516 + 4*c4];
  } else if (i < 133128) {               // Wfc
    int o = i - 66564; int c4 = o / 516, j = o % 516;
    Wfcp[o] = *(const float4*)&Wfc[(size_t)j*516 + 4*c4];
  } else if (i < 162712) {               // W1: 172 c4 x 172 j
    int o = i - 133128; int c4 = o / 172, j = o % 172;
    W1p[o] = *(const float4*)&W1[(size_t)j*688 + 4*c4];
  } else if (i < 170108) {               // W2: 43 c4 x 172 j
    int o = i - 162712; int c4 = o / 172, j = o % 172;
    W2p[o] = *(const float4*)&W2[(size_t)j*172 + 4*c4];
  } else if (i < 171140) {               // u: 2 x 516
    int o = i - 170108; int h = o / 516, c = o % 516;
    float s = 0.f;
    for (int d = 0; d < 258; ++d)
      s += Wk[(size_t)(h*258 + d)*516 + c] * wmap[258 + d];
    u[o] = s;
  }
}

// ---------------------------------------------------------------------------
// kernel 1: per-b attention. Streams k_in = [seq|seq_e|seq_t] in 16-row LDS
// chunks; sk = row . u_h; p = exp(sk) (no max-subtract, |sk| small);
// ctxin accumulated unnormalized in registers, normalized at end.
// LDS ~38KB -> 4 blocks/CU.
// ---------------------------------------------------------------------------
__global__ __launch_bounds__(256) void attn_kernel(
    const float* __restrict__ seq, const float* __restrict__ seqe,
    const float* __restrict__ seqt, const unsigned char* __restrict__ mask,
    const float* __restrict__ ws, float* __restrict__ ctxin,
    float* __restrict__ attn_out)
{
  __shared__ float buf[16*516];   // 16 rows x [seq(172)|e(172)|t(172)]; stride 516 = 4*129 (odd f4) -> good banking
  __shared__ float u_l[1032];
  __shared__ float p2[32];        // exp(sk) current chunk: [k16][h]
  __shared__ float pall[128];     // all 64 k: [k][h]
  __shared__ float sinv_l[2];

  const float* u = ws + OFF_U;
  int t = threadIdx.x;
  int b = blockIdx.x;

  for (int i = t; i < 258; i += 256) ((float4*)u_l)[i] = ((const float4*)u)[i];

  // thread-owned float2 columns of ctxin (258 f2 cols; t<2 own a second one)
  float2 a0 = {0.f,0.f}, a1 = {0.f,0.f}, e0 = {0.f,0.f}, e1 = {0.f,0.f};

  const float* g0b = seq  + (size_t)b*64*172;
  const float* g1b = seqe + (size_t)b*64*172;
  const float* g2b = seqt + (size_t)b*64*172;

  int sub = t & 7, pr = t >> 3;          // 32 (h,k) pairs x 8-way c-split
  int hB = pr >> 4, kB = pr & 15;
  int startB = (sub == 0) ? 0 : (16*sub + 1);
  int cntB   = (sub == 0) ? 17 : 16;     // 17 + 7*16 = 129 f4

  for (int chunk = 0; chunk < 4; ++chunk) {
    int kk0 = chunk*16;
    { // stage 16 rows (3 tensors x 688 f4, coalesced)
      const float4* g0 = (const float4*)(g0b + (size_t)kk0*172);
      const float4* g1 = (const float4*)(g1b + (size_t)kk0*172);
      const float4* g2 = (const float4*)(g2b + (size_t)kk0*172);
      for (int f = t; f < 688; f += 256) {
        int r = f / 43, c4 = f - r*43;
        float4 v0 = g0[f], v1 = g1[f], v2 = g2[f];
        *(float4*)&buf[r*516 +       c4*4] = v0;
        *(float4*)&buf[r*516 + 172 + c4*4] = v1;
        *(float4*)&buf[r*516 + 344 + c4*4] = v2;
      }
    }
    __syncthreads();
    { // phase B: sk -> p
      float s = 0.f;
      const float4* row4 = (const float4*)&buf[kB*516];
      const float4* u4   = (const float4*)&u_l[hB*516];
      for (int ii = 0; ii < cntB; ++ii) {
        float4 a = row4[startB + ii];
        float4 w = u4[startB + ii];
        s += a.x*w.x + a.y*w.y + a.z*w.z + a.w*w.w;
      }
      s += __shfl_xor(s, 1);
      s += __shfl_xor(s, 2);
      s += __shfl_xor(s, 4);
      if (sub == 0) {
        int kk = kk0 + kB;
        float pv = mask[(size_t)b*64 + kk] ? 0.f : expf(s);
        p2[kB*2 + hB] = pv;
        pall[kk*2 + hB] = pv;
      }
    }
    __syncthreads();
    { // phase C: ctxin += p * row
      #pragma unroll 4
      for (int k = 0; k < 16; ++k) {
        float2 p = *(const float2*)&p2[k*2];
        float2 v = *(const float2*)&buf[k*516 + 2*t];
        a0.x += p.x*v.x; a0.y += p.x*v.y;
        a1.x += p.y*v.x; a1.y += p.y*v.y;
        if (t < 2) {
          float2 v2 = *(const float2*)&buf[k*516 + 2*(256+t)];
          e0.x += p.x*v2.x; e0.y += p.x*v2.y;
          e1.x += p.y*v2.x; e1.y += p.y*v2.y;
        }
      }
    }
    __syncthreads();
  }
  // epilogue: softmax denominators + attn_out
  if (t < 128) {
    int h = t >> 6, k = t & 63;
    float pv = pall[k*2 + h];
    float ssum = pv;
    #pragma unroll
    for (int off = 1; off < 64; off <<= 1) ssum += __shfl_xor(ssum, off);
    attn_out[((size_t)h*B_ + b)*64 + k] = pv / ssum;
    if (k == 0) sinv_l[h] = 1.f / ssum;
  }
  __syncthreads();
  float s0 = sinv_l[0], s1 = sinv_l[1];
  float* cb = ctxin + (size_t)b*1032;
  *(float2*)&cb[2*t]       = make_float2(a0.x*s0, a0.y*s0);
  *(float2*)&cb[516 + 2*t] = make_float2(a1.x*s1, a1.y*s1);
  if (t < 2) {
    *(float2*)&cb[2*(256+t)]       = make_float2(e0.x*s0, e0.y*s0);
    *(float2*)&cb[516 + 2*(256+t)] = make_float2(e1.x*s1, e1.y*s1);
  }
}

// ---------------------------------------------------------------------------
// kernel 2: per-16-row chain. thread j = output column; 16 row-accumulators;
// A-operand broadcast b128 from LDS, weights coalesced float4 from L2.
// ctx = ctxin x Wv  ->  t2 = ctx x Wfc -> leaky+q_in -> LN -> m=[out|src]
// -> relu(m x W1 + b1) -> x W2 + b2 -> final.
// ---------------------------------------------------------------------------
__global__ __launch_bounds__(576) void chain_kernel(
    const float* __restrict__ ws, const float* __restrict__ src,
    const float* __restrict__ srct,
    const float* __restrict__ bfc, const float* __restrict__ lng,
    const float* __restrict__ lnb, const float* __restrict__ b1,
    const float* __restrict__ b2, float* __restrict__ finalout)
{
  __shared__ float A[16*1032];    // ctxin tile -> later M tile [16][688] -> later Hm [16][172]
  __shared__ float Ctx[16*516];   // ctx tile -> later P3 [3][16][172] (8256 floats, exact fit)
  __shared__ float Red[9*16*2];
  __shared__ float MuSig[32];

  const float*  ctxin = ws + OFF_CTXIN;
  const float4* Wvp   = (const float4*)(ws + OFF_WVP);
  const float4* Wfcp  = (const float4*)(ws + OFF_WFCP);
  const float4* W1p   = (const float4*)(ws + OFF_W1P);
  const float4* W2p   = (const float4*)(ws + OFF_W2P);

  int t = threadIdx.x;
  int b0 = blockIdx.x * 16;

  { // stage ctxin tile (4128 f4, coalesced)
    const float4* g = (const float4*)(ctxin + (size_t)b0*1032);
    float4* a4 = (float4*)A;
    for (int f = t; f < 4128; f += 576) a4[f] = g[f];
  }
  __syncthreads();

  int j = t;
  bool actj = (j < 516);
  int hh = (j < 258) ? 0 : 1;
  float acc[16];
  #pragma unroll
  for (int r = 0; r < 16; ++r) acc[r] = 0.f;
  if (actj) { // GEMM1: ctx
    const float* Ab = &A[hh*516];
    for (int c4 = 0; c4 < 129; ++c4) {
      float4 w = Wvp[c4*516 + j];
      #pragma unroll
      for (int r = 0; r < 16; ++r) {
        float4 a = *(const float4*)&Ab[r*1032 + 4*c4];
        acc[r] += a.x*w.x + a.y*w.y + a.z*w.z + a.w*w.w;
      }
    }
    #pragma unroll
    for (int r = 0; r < 16; ++r) Ctx[r*516 + j] = acc[r];
  }
  __syncthreads();

  // GEMM2: ctx x Wfc
  #pragma unroll
  for (int r = 0; r < 16; ++r) acc[r] = 0.f;
  if (actj) {
    for (int c4 = 0; c4 < 129; ++c4) {
      float4 w = Wfcp[c4*516 + j];
      #pragma unroll
      for (int r = 0; r < 16; ++r) {
        float4 a = *(const float4*)&Ctx[r*516 + 4*c4];
        acc[r] += a.x*w.x + a.y*w.y + a.z*w.z + a.w*w.w;
      }
    }
  }
  float bfcj = actj ? bfc[j] : 0.f;
  float x[16];
  #pragma unroll
  for (int r = 0; r < 16; ++r) {
    float v = acc[r] + bfcj;
    v = (v > 0.f) ? v : 0.2f*v;          // leaky_relu(0.2)
    float q = 0.f;
    if (j < 172)                        q = src[(size_t)(b0+r)*172 + j];
    else if (j >= 344 && j < 516)       q = srct[(size_t)(b0+r)*172 + (j - 344)];
    x[r] = actj ? (v + q) : 0.f;
  }
  // LayerNorm stats: per-wave shuffle reduce -> LDS -> 16 threads finish
  int wv = t >> 6, lane = t & 63;
  #pragma unroll
  for (int r = 0; r < 16; ++r) {
    float s = x[r], q = x[r]*x[r];
    #pragma unroll
    for (int off = 1; off < 64; off <<= 1) { s += __shfl_xor(s, off); q += __shfl_xor(q, off); }
    if (lane == 0) { Red[(wv*16 + r)*2] = s; Red[(wv*16 + r)*2 + 1] = q; }
  }
  __syncthreads();
  if (t < 16) {
    float s = 0.f, q = 0.f;
    for (int w = 0; w < 9; ++w) { s += Red[(w*16 + t)*2]; q += Red[(w*16 + t)*2 + 1]; }
    float mu  = s * (1.f/516.f);
    float var = q * (1.f/516.f) - mu*mu;
    MuSig[t*2]   = mu;
    MuSig[t*2+1] = rsqrtf(var + 1e-5f);
  }
  __syncthreads();
  // M tile = [LN_out(516) | src(172)]  (A region; ctxin tile is dead)
  float* M = A;
  if (actj) {
    float lg = lng[j], lb = lnb[j];
    #pragma unroll
    for (int r = 0; r < 16; ++r)
      M[r*688 + j] = (x[r] - MuSig[r*2]) * MuSig[r*2+1] * lg + lb;
  }
  for (int i = t; i < 2752; i += 576) {
    int r = i / 172, c = i - r*172;
    M[r*688 + 516 + c] = src[(size_t)(b0 + r)*172 + c];
  }
  __syncthreads();

  { // GEMM3: m x W1, 3-way k-split (516 threads), partials into P3 (=Ctx region)
    float acc3[16];
    #pragma unroll
    for (int r = 0; r < 16; ++r) acc3[r] = 0.f;
    if (actj) {
      int j3 = t % 172, seg = t / 172;
      int c4lo = (seg == 0) ? 0  : ((seg == 1) ? 58  : 115);
      int c4hi = (seg == 0) ? 58 : ((seg == 1) ? 115 : 172);
      for (int c4 = c4lo; c4 < c4hi; ++c4) {
        float4 w = W1p[c4*172 + j3];
        #pragma unroll
        for (int r = 0; r < 16; ++r) {
          float4 a = *(const float4*)&M[r*688 + 4*c4];
          acc3[r] += a.x*w.x + a.y*w.y + a.z*w.z + a.w*w.w;
        }
      }
      float* P3 = Ctx;
      #pragma unroll
      for (int r = 0; r < 16; ++r) P3[(seg*16 + r)*172 + j3] = acc3[r];
    }
  }
  __syncthreads();
  // reduce partials + bias + relu -> Hm (A region; M is dead)
  float* Hm = A;
  for (int i = t; i < 2752; i += 576) {
    int r = i / 172, c = i - r*172;
    float v = Ctx[r*172 + c] + Ctx[(16 + r)*172 + c] + Ctx[(32 + r)*172 + c] + b1[c];
    Hm[r*172 + c] = (v > 0.f) ? v : 0.f;
  }
  __syncthreads();

  if (t < 172) { // GEMM4: hm x W2 -> final
    float acc4[16];
    #pragma unroll
    for (int r = 0; r < 16; ++r) acc4[r] = 0.f;
    for (int c4 = 0; c4 < 43; ++c4) {
      float4 w = W2p[c4*172 + t];
      #pragma unroll
      for (int r = 0; r < 16; ++r) {
        float4 a = *(const float4*)&Hm[r*172 + 4*c4];
        acc4[r] += a.x*w.x + a.y*w.y + a.z*w.z + a.w*w.w;
      }
    }
    float bb = b2[t];
    #pragma unroll
    for (int r = 0; r < 16; ++r)
      finalout[(size_t)(b0 + r)*172 + t] = acc4[r] + bb;
  }
}

extern "C" void kernel_launch(void* const* d_in, const int* in_sizes, int n_in,
                              void* d_out, int out_size, void* d_ws, size_t ws_size,
                              hipStream_t stream) {
  (void)in_sizes; (void)n_in; (void)out_size; (void)ws_size;
  const float* src  = (const float*)d_in[0];
  const float* srct = (const float*)d_in[1];
  const float* seq  = (const float*)d_in[2];
  const float* seqt = (const float*)d_in[3];
  const float* seqe = (const float*)d_in[4];
  const unsigned char* mask = (const unsigned char*)d_in[5];
  // d_in[6] = Wq — provably unused (softmax is shift-invariant in the query term)
  const float* Wk   = (const float*)d_in[7];
  const float* Wv   = (const float*)d_in[8];
  const float* wmap = (const float*)d_in[9];
  const float* Wfc  = (const float*)d_in[10];
  const float* bfc  = (const float*)d_in[11];
  const float* lng  = (const float*)d_in[12];
  const float* lnb  = (const float*)d_in[13];
  const float* W1   = (const float*)d_in[14];
  const float* b1   = (const float*)d_in[15];
  const float* W2   = (const float*)d_in[16];
  const float* b2   = (const float*)d_in[17];

  float* ws = (float*)d_ws;
  float* out = (float*)d_out;
  float* attn_out = out + (size_t)B_*FEAT_;   // final (4096x172) then attn (8192x64)
  float* ctxin = ws + OFF_CTXIN;

  prep_kernel <<<669, 256, 0, stream>>>(Wk, wmap, Wv, Wfc, W1, W2, ws);
  attn_kernel <<<B_, 256, 0, stream>>>(seq, seqe, seqt, mask, ws, ctxin, attn_out);
  chain_kernel<<<B_/16, 576, 0, stream>>>(ws, src, srct, bfc, lng, lnb, b1, b2, out);
}

// Round 2
// 667.515 us; speedup vs baseline: 1.1604x; 1.1604x over previous
//
#include <hip/hip_runtime.h>
#include <cstddef>

#define B_    4096
#define FEAT_ 172

// workspace layout (float offsets)
#define OFF_U      0
#define OFF_WCS    1032                                   // 608256 halves = 304128 floats (36 tiles x 33 ksteps)
#define OFF_W1S    (1032 + 304128)                        // 135168 halves = 67584 floats  (12 tiles x 22 ksteps)
#define OFF_W2S    (1032 + 304128 + 67584)                // 36864 halves  = 18432 floats  (12 tiles x 6 ksteps)
#define OFF_CTXIN  (1032 + 304128 + 67584 + 18432)        // 4096*1032 floats
// total = 391176 + 4227072 = 4,618,248 floats (~18.5 MiB) <= R1's 4,908,536 (ws_size proven adequate)

typedef __attribute__((ext_vector_type(8))) short short8;   // 8 bf16 (4 VGPRs) — MFMA A/B frag
typedef __attribute__((ext_vector_type(4))) float f32x4;    // MFMA C/D frag

__device__ inline unsigned short f2bf(float f) {            // fp32 -> bf16 RNE
  union { float f; unsigned u; } v; v.f = f;
  unsigned r = v.u + 0x7FFFu + ((v.u >> 16) & 1u);
  return (unsigned short)(r >> 16);
}

// ---------------------------------------------------------------------------
// zero_wcs: zero the Wcomb swizzle region (padding tiles/ksteps must be 0)
// ---------------------------------------------------------------------------
__global__ __launch_bounds__(256) void zero_wcs(float* __restrict__ ws) {
  int i = blockIdx.x * 256 + threadIdx.x;        // 76032 f4 exactly (297 blocks)
  float4* p = (float4*)(ws + OFF_WCS);
  p[i] = make_float4(0.f, 0.f, 0.f, 0.f);
}

// ---------------------------------------------------------------------------
// prep_u: u[h][c] = sum_d Wk[h*258+d][c] * w_map[258+d]   (coalesced over c)
// ---------------------------------------------------------------------------
__global__ __launch_bounds__(256) void prep_u(
    const float* __restrict__ Wk, const float* __restrict__ wmap,
    float* __restrict__ ws) {
  int i = blockIdx.x * 256 + threadIdx.x;
  if (i >= 1032) return;
  int h = i / 516, c = i % 516;
  float s = 0.f;
  for (int d = 0; d < 258; ++d)
    s += Wk[(size_t)(h*258 + d)*516 + c] * wmap[258 + d];
  ws[OFF_U + i] = s;
}

// ---------------------------------------------------------------------------
// prep_wcomb: Wcomb[j][h*516+c] = sum_d Wfc[j][h*258+d] * Wv[h*258+d][c],
// written bf16 into B-frag swizzle: idx = ((tile*33+kstep)*64 + quad*16 + (j&15))*8 + (k&7)
// where tile=j>>4, k = h*516+c, kstep=k>>5, quad=(k>>3)&3.
// 4 j-rows per block reuse each Wv row load 4x.
// ---------------------------------------------------------------------------
__global__ __launch_bounds__(256) void prep_wcomb(
    const float* __restrict__ Wfc, const float* __restrict__ Wv,
    float* __restrict__ ws) {
  int blk = blockIdx.x;                 // 258 = 129 j-groups x 2 heads
  int j0 = (blk >> 1) * 4, h = blk & 1;
  int t = threadIdx.x;
  unsigned short* Wcs = (unsigned short*)(ws + OFF_WCS);
  float s0[4] = {0,0,0,0}, s1[4] = {0,0,0,0}, s2[4] = {0,0,0,0};
  for (int d = 0; d < 258; ++d) {
    const float* wv = Wv + (size_t)(h*258 + d)*516;
    float v0 = wv[t], v1 = wv[256 + t];
    float v2 = (t < 4) ? wv[512 + t] : 0.f;
    #pragma unroll
    for (int jj = 0; jj < 4; ++jj) {
      float f = Wfc[(size_t)(j0 + jj)*516 + h*258 + d];  // wave-uniform scalar
      s0[jj] += f*v0; s1[jj] += f*v1; s2[jj] += f*v2;
    }
  }
  #pragma unroll
  for (int jj = 0; jj < 4; ++jj) {
    int j = j0 + jj;
    int tile = j >> 4, jlow = j & 15;
    int k;
    k = h*516 + t;
    Wcs[(((tile*33 + (k>>5))*64 + ((k>>3)&3)*16 + jlow) << 3) + (k&7)] = f2bf(s0[jj]);
    k = h*516 + 256 + t;
    Wcs[(((tile*33 + (k>>5))*64 + ((k>>3)&3)*16 + jlow) << 3) + (k&7)] = f2bf(s1[jj]);
    if (t < 4) {
      k = h*516 + 512 + t;
      Wcs[(((tile*33 + (k>>5))*64 + ((k>>3)&3)*16 + jlow) << 3) + (k&7)] = f2bf(s2[jj]);
    }
  }
}

// ---------------------------------------------------------------------------
// prep_w1w2: swizzle W1 (172x688 -> 12 tiles x 22 ksteps) and W2 (172x172 ->
// 12 tiles x 6 ksteps) into bf16 B-frag layout; out-of-range -> 0.
// One thread per (tile,kstep,lane) writes 8 halves (16B coalesced).
// ---------------------------------------------------------------------------
__global__ __launch_bounds__(256) void prep_w1w2(
    const float* __restrict__ W1, const float* __restrict__ W2,
    float* __restrict__ ws) {
  int idx = blockIdx.x * 256 + threadIdx.x;
  unsigned short* W1s = (unsigned short*)(ws + OFF_W1S);
  unsigned short* W2s = (unsigned short*)(ws + OFF_W2S);
  if (idx < 16896) {                               // 12*22*64
    int lane = idx & 63, rest = idx >> 6;
    int ks = rest % 22, tile = rest / 22;
    int n = tile*16 + (lane & 15);
    int k0 = ks*32 + (lane >> 4)*8;
    union { unsigned short u[8]; uint4 v; } pk;
    #pragma unroll
    for (int j = 0; j < 8; ++j) {
      int k = k0 + j;
      float v = (n < 172 && k < 688) ? W1[(size_t)n*688 + k] : 0.f;
      pk.u[j] = f2bf(v);
    }
    ((uint4*)W1s)[idx] = pk.v;
  } else if (idx < 16896 + 4608) {                 // 12*6*64
    int o = idx - 16896;
    int lane = o & 63, rest = o >> 6;
    int ks = rest % 6, tile = rest / 6;
    int n = tile*16 + (lane & 15);
    int k0 = ks*32 + (lane >> 4)*8;
    union { unsigned short u[8]; uint4 v; } pk;
    #pragma unroll
    for (int j = 0; j < 8; ++j) {
      int k = k0 + j;
      float v = (n < 172 && k < 172) ? W2[(size_t)n*172 + k] : 0.f;
      pk.u[j] = f2bf(v);
    }
    ((uint4*)W2s)[o] = pk.v;
  }
}

// ---------------------------------------------------------------------------
// kernel 1: per-b attention (unchanged from R1 — passed; HBM-compulsory 541MB).
// ---------------------------------------------------------------------------
__global__ __launch_bounds__(256) void attn_kernel(
    const float* __restrict__ seq, const float* __restrict__ seqe,
    const float* __restrict__ seqt, const unsigned char* __restrict__ mask,
    const float* __restrict__ ws, float* __restrict__ ctxin,
    float* __restrict__ attn_out)
{
  __shared__ float buf[16*516];
  __shared__ float u_l[1032];
  __shared__ float p2[32];
  __shared__ float pall[128];
  __shared__ float sinv_l[2];

  const float* u = ws + OFF_U;
  int t = threadIdx.x;
  int b = blockIdx.x;

  for (int i = t; i < 258; i += 256) ((float4*)u_l)[i] = ((const float4*)u)[i];

  float2 a0 = {0.f,0.f}, a1 = {0.f,0.f}, e0 = {0.f,0.f}, e1 = {0.f,0.f};

  const float* g0b = seq  + (size_t)b*64*172;
  const float* g1b = seqe + (size_t)b*64*172;
  const float* g2b = seqt + (size_t)b*64*172;

  int sub = t & 7, pr = t >> 3;
  int hB = pr >> 4, kB = pr & 15;
  int startB = (sub == 0) ? 0 : (16*sub + 1);
  int cntB   = (sub == 0) ? 17 : 16;

  for (int chunk = 0; chunk < 4; ++chunk) {
    int kk0 = chunk*16;
    {
      const float4* g0 = (const float4*)(g0b + (size_t)kk0*172);
      const float4* g1 = (const float4*)(g1b + (size_t)kk0*172);
      const float4* g2 = (const float4*)(g2b + (size_t)kk0*172);
      for (int f = t; f < 688; f += 256) {
        int r = f / 43, c4 = f - r*43;
        float4 v0 = g0[f], v1 = g1[f], v2 = g2[f];
        *(float4*)&buf[r*516 +       c4*4] = v0;
        *(float4*)&buf[r*516 + 172 + c4*4] = v1;
        *(float4*)&buf[r*516 + 344 + c4*4] = v2;
      }
    }
    __syncthreads();
    {
      float s = 0.f;
      const float4* row4 = (const float4*)&buf[kB*516];
      const float4* u4   = (const float4*)&u_l[hB*516];
      for (int ii = 0; ii < cntB; ++ii) {
        float4 a = row4[startB + ii];
        float4 w = u4[startB + ii];
        s += a.x*w.x + a.y*w.y + a.z*w.z + a.w*w.w;
      }
      s += __shfl_xor(s, 1);
      s += __shfl_xor(s, 2);
      s += __shfl_xor(s, 4);
      if (sub == 0) {
        int kk = kk0 + kB;
        float pv = mask[(size_t)b*64 + kk] ? 0.f : expf(s);
        p2[kB*2 + hB] = pv;
        pall[kk*2 + hB] = pv;
      }
    }
    __syncthreads();
    {
      #pragma unroll 4
      for (int k = 0; k < 16; ++k) {
        float2 p = *(const float2*)&p2[k*2];
        float2 v = *(const float2*)&buf[k*516 + 2*t];
        a0.x += p.x*v.x; a0.y += p.x*v.y;
        a1.x += p.y*v.x; a1.y += p.y*v.y;
        if (t < 2) {
          float2 v2 = *(const float2*)&buf[k*516 + 2*(256+t)];
          e0.x += p.x*v2.x; e0.y += p.x*v2.y;
          e1.x += p.y*v2.x; e1.y += p.y*v2.y;
        }
      }
    }
    __syncthreads();
  }
  if (t < 128) {
    int h = t >> 6, k = t & 63;
    float pv = pall[k*2 + h];
    float ssum = pv;
    #pragma unroll
    for (int off = 1; off < 64; off <<= 1) ssum += __shfl_xor(ssum, off);
    attn_out[((size_t)h*B_ + b)*64 + k] = pv / ssum;
    if (k == 0) sinv_l[h] = 1.f / ssum;
  }
  __syncthreads();
  float s0 = sinv_l[0], s1 = sinv_l[1];
  float* cb = ctxin + (size_t)b*1032;
  *(float2*)&cb[2*t]       = make_float2(a0.x*s0, a0.y*s0);
  *(float2*)&cb[516 + 2*t] = make_float2(a1.x*s1, a1.y*s1);
  if (t < 2) {
    *(float2*)&cb[2*(256+t)]       = make_float2(e0.x*s0, e0.y*s0);
    *(float2*)&cb[516 + 2*(256+t)] = make_float2(e1.x*s1, e1.y*s1);
  }
}

// ---------------------------------------------------------------------------
// kernel 2: MFMA chain. 16 rows/block, 4 waves. A-frags in LDS (swizzled bf16),
// B-frags streamed from L2 in pre-swizzled layout.
//   GEMM-A: t2[16x516] = ctxin[16x1032] x Wcomb^T   (33 ntiles incl pad, 33 ksteps)
//   epi-A : +bfc, leaky(0.2), +q_in, LayerNorm      (C-layout: col=lane&15, row=quad*4+reg)
//   GEMM-B: hm[16x172] = M[16x688] x W1^T  (+b1, relu)
//   GEMM-C: final = hm x W2^T + b2
// LDS ~41KB.
// ---------------------------------------------------------------------------
__global__ __launch_bounds__(256) void chain_kernel(
    const float* __restrict__ ws, const float* __restrict__ src,
    const float* __restrict__ srct, const float* __restrict__ bfc,
    const float* __restrict__ lng, const float* __restrict__ lnb,
    const float* __restrict__ b1, const float* __restrict__ b2,
    float* __restrict__ finalout)
{
  __shared__ __align__(16) unsigned short AM[33*512];   // A_s (33 ks) -> reused as M_s (22 ks)
  __shared__ __align__(16) unsigned short HM[6*512];    // Hm_s (6 ks)
  __shared__ float Red[128];
  __shared__ float MuSig[32];

  const unsigned short* Wcs = (const unsigned short*)(ws + OFF_WCS);
  const unsigned short* W1s = (const unsigned short*)(ws + OFF_W1S);
  const unsigned short* W2s = (const unsigned short*)(ws + OFF_W2S);
  const float* ctxin = ws + OFF_CTXIN;

  int t = threadIdx.x;
  int lane = t & 63, w = t >> 6;
  int b0 = blockIdx.x * 16;
  int cq = lane >> 4;        // quad
  int cl = lane & 15;        // col (C-layout) / row (A staging)

  // phase 0: stage A swizzled bf16; zero A pad (ks32 lanes16..63) and HM ks5
  {
    const float4* g = (const float4*)(ctxin + (size_t)b0 * 1032);
    for (int f = t; f < 4128; f += 256) {
      int r = f / 258, c4 = f - r*258;
      float4 v = g[f];
      int k = c4 * 4;
      int addr = (((k >> 5)*64 + ((k >> 3) & 3)*16 + r) << 3) + (k & 7);
      union { unsigned short u[4]; uint2 v2; } pk;
      pk.u[0] = f2bf(v.x); pk.u[1] = f2bf(v.y); pk.u[2] = f2bf(v.z); pk.u[3] = f2bf(v.w);
      *(uint2*)&AM[addr] = pk.v2;
    }
    for (int i = t; i < 384; i += 256)
      AM[((32*64 + 16 + (i >> 3)) << 3) + (i & 7)] = 0;   // k 1032..1055
    for (int i = t; i < 512; i += 256)
      HM[5*512 + i] = 0;                                   // k 160..191 (valid parts overwritten later)
  }
  __syncthreads();  // #1

  // GEMM-A: wave w owns ntiles {w, w+4, ..., w+32} (tiles>=33 are zero-padded)
  f32x4 acc[9];
  #pragma unroll
  for (int i = 0; i < 9; ++i) acc[i] = (f32x4){0.f, 0.f, 0.f, 0.f};
  for (int ks = 0; ks < 33; ++ks) {
    short8 a = *(const short8*)&AM[(ks*64 + lane) << 3];
    #pragma unroll
    for (int i = 0; i < 9; ++i) {
      int tile = w + 4*i;
      short8 b = *(const short8*)&Wcs[(size_t)((tile*33 + ks)*64 + lane) << 3];
      acc[i] = __builtin_amdgcn_mfma_f32_16x16x32_bf16(a, b, acc[i], 0, 0, 0);
    }
  }

  // epilogue A: bias + leaky + residual; per-row LN partial sums
  float x[9][4];
  float sum[4] = {0,0,0,0}, ssq[4] = {0,0,0,0};
  #pragma unroll
  for (int i = 0; i < 9; ++i) {
    int col = (w + 4*i)*16 + cl;
    bool valid = col < 516;
    float bv = valid ? bfc[col] : 0.f;
    #pragma unroll
    for (int r = 0; r < 4; ++r) {
      float v = acc[i][r] + bv;
      v = (v > 0.f) ? v : 0.2f*v;
      float qin = 0.f;
      if (valid) {
        int row = b0 + cq*4 + r;
        if (col < 172)       qin = src[(size_t)row*172 + col];
        else if (col >= 344) qin = srct[(size_t)row*172 + (col - 344)];
      }
      float xv = valid ? (v + qin) : 0.f;
      x[i][r] = xv;
      sum[r] += xv; ssq[r] += xv*xv;
    }
  }
  #pragma unroll
  for (int o = 1; o < 16; o <<= 1) {
    #pragma unroll
    for (int r = 0; r < 4; ++r) {
      sum[r] += __shfl_xor(sum[r], o);
      ssq[r] += __shfl_xor(ssq[r], o);
    }
  }
  if (cl == 0) {
    #pragma unroll
    for (int r = 0; r < 4; ++r) {
      Red[(w*16 + cq*4 + r)*2    ] = sum[r];
      Red[(w*16 + cq*4 + r)*2 + 1] = ssq[r];
    }
  }
  __syncthreads();  // #2 — A_s dead past here

  if (t < 16) {
    float s = 0.f, qq = 0.f;
    for (int wv = 0; wv < 4; ++wv) { s += Red[(wv*16 + t)*2]; qq += Red[(wv*16 + t)*2 + 1]; }
    float mu  = s * (1.f/516.f);
    float var = qq * (1.f/516.f) - mu*mu;
    MuSig[t*2]   = mu;
    MuSig[t*2+1] = rsqrtf(var + 1e-5f);
  }
  // stage src part of M (k = 516..687) + zero M pad (k 688..703)
  for (int i = t; i < 2752; i += 256) {
    int r = i / 172, c = i - r*172;
    int k = 516 + c;
    AM[(((k >> 5)*64 + ((k >> 3) & 3)*16 + r) << 3) + (k & 7)] =
        f2bf(src[(size_t)(b0 + r)*172 + c]);
  }
  AM[((21*64 + 32 + (t >> 3)) << 3) + (t & 7)] = 0;   // 256 halves, k 688..703
  __syncthreads();  // #3

  // apply LN -> M LN part (k = 0..515)
  #pragma unroll
  for (int i = 0; i < 9; ++i) {
    int col = (w + 4*i)*16 + cl;
    if (col < 516) {
      float lg = lng[col], lb = lnb[col];
      #pragma unroll
      for (int r = 0; r < 4; ++r) {
        int row = cq*4 + r;
        float m = (x[i][r] - MuSig[row*2]) * MuSig[row*2+1] * lg + lb;
        AM[(((col >> 5)*64 + ((col >> 3) & 3)*16 + row) << 3) + (col & 7)] = f2bf(m);
      }
    }
  }
  __syncthreads();  // #4

  // GEMM-B: 12 ntiles over 4 waves (3 each), 22 ksteps
  f32x4 accB[3];
  #pragma unroll
  for (int i = 0; i < 3; ++i) accB[i] = (f32x4){0.f, 0.f, 0.f, 0.f};
  for (int ks = 0; ks < 22; ++ks) {
    short8 a = *(const short8*)&AM[(ks*64 + lane) << 3];
    #pragma unroll
    for (int i = 0; i < 3; ++i) {
      int tile = w + 4*i;
      short8 b = *(const short8*)&W1s[(size_t)((tile*22 + ks)*64 + lane) << 3];
      accB[i] = __builtin_amdgcn_mfma_f32_16x16x32_bf16(a, b, accB[i], 0, 0, 0);
    }
  }
  // relu + b1 -> HM (separate region; pad pre-zeroed in phase 0)
  #pragma unroll
  for (int i = 0; i < 3; ++i) {
    int col = (w + 4*i)*16 + cl;
    if (col < 172) {
      float bb = b1[col];
      #pragma unroll
      for (int r = 0; r < 4; ++r) {
        float v = accB[i][r] + bb;
        v = (v > 0.f) ? v : 0.f;
        HM[(((col >> 5)*64 + ((col >> 3) & 3)*16 + (cq*4 + r)) << 3) + (col & 7)] = f2bf(v);
      }
    }
  }
  __syncthreads();  // #5

  // GEMM-C: 12 ntiles over 4 waves, 6 ksteps
  f32x4 accC[3];
  #pragma unroll
  for (int i = 0; i < 3; ++i) accC[i] = (f32x4){0.f, 0.f, 0.f, 0.f};
  for (int ks = 0; ks < 6; ++ks) {
    short8 a = *(const short8*)&HM[(ks*64 + lane) << 3];
    #pragma unroll
    for (int i = 0; i < 3; ++i) {
      int tile = w + 4*i;
      short8 b = *(const short8*)&W2s[(size_t)((tile*6 + ks)*64 + lane) << 3];
      accC[i] = __builtin_amdgcn_mfma_f32_16x16x32_bf16(a, b, accC[i], 0, 0, 0);
    }
  }
  #pragma unroll
  for (int i = 0; i < 3; ++i) {
    int col = (w + 4*i)*16 + cl;
    if (col < 172) {
      float bb = b2[col];
      #pragma unroll
      for (int r = 0; r < 4; ++r)
        finalout[(size_t)(b0 + cq*4 + r)*172 + col] = accC[i][r] + bb;
    }
  }
}

extern "C" void kernel_launch(void* const* d_in, const int* in_sizes, int n_in,
                              void* d_out, int out_size, void* d_ws, size_t ws_size,
                              hipStream_t stream) {
  (void)in_sizes; (void)n_in; (void)out_size; (void)ws_size;
  const float* src  = (const float*)d_in[0];
  const float* srct = (const float*)d_in[1];
  const float* seq  = (const float*)d_in[2];
  const float* seqt = (const float*)d_in[3];
  const float* seqe = (const float*)d_in[4];
  const unsigned char* mask = (const unsigned char*)d_in[5];
  // d_in[6] = Wq — unused (softmax shift-invariance)
  const float* Wk   = (const float*)d_in[7];
  const float* Wv   = (const float*)d_in[8];
  const float* wmap = (const float*)d_in[9];
  const float* Wfc  = (const float*)d_in[10];
  const float* bfc  = (const float*)d_in[11];
  const float* lng  = (const float*)d_in[12];
  const float* lnb  = (const float*)d_in[13];
  const float* W1   = (const float*)d_in[14];
  const float* b1   = (const float*)d_in[15];
  const float* W2   = (const float*)d_in[16];
  const float* b2   = (const float*)d_in[17];

  float* ws  = (float*)d_ws;
  float* out = (float*)d_out;
  float* attn_out = out + (size_t)B_*FEAT_;
  float* ctxin = ws + OFF_CTXIN;

  zero_wcs   <<<297, 256, 0, stream>>>(ws);
  prep_u     <<<5,   256, 0, stream>>>(Wk, wmap, ws);
  prep_wcomb <<<258, 256, 0, stream>>>(Wfc, Wv, ws);
  prep_w1w2  <<<84,  256, 0, stream>>>(W1, W2, ws);
  attn_kernel<<<B_,  256, 0, stream>>>(seq, seqe, seqt, mask, ws, ctxin, attn_out);
  chain_kernel<<<B_/16, 256, 0, stream>>>(ws, src, srct, bfc, lng, lnb, b1, b2, out);
}